// Round 8
// baseline (188.362 us; speedup 1.0000x reference)
//
#include <hip/hip_runtime.h>

#define IMG_H 512
#define IMG_W 512
#define HW (IMG_H * IMG_W)
#define NB 32

// Workspace layout:
//   acc[0..31]    lap_sum     acc[32..63]  lap_sumsq
//   acc[64..95]   depth_n     acc[96..127] depth_sum   acc[128..159] depth_sumsq
//   hist: 32*256 uint at byte offset 160*8
//   gray plane: 32*512*512 float at byte offset 65536
#define ACC_DOUBLES 160
#define ZERO_BYTES (ACC_DOUBLES * 8 + NB * 256 * 4)
#define GRAY_OFF 65536

// ---------------- k1: m13-clone streaming pass ----------------
// Grid 64 x 32. Block x covers float4s [x*1024,(x+1)*1024) of image b's
// planes; thread t handles 4 independent float4-quads at stride 256.
// Reads r,g,b,depth coalesced; writes gray; LDS per-wave histogram; depth
// moments. All 16 loads/thread independent -> flat issue, deep MLP.
__global__ __launch_bounds__(256, 4) void gray_hist_depth_kernel(
    const float* __restrict__ rgb, const float* __restrict__ depth,
    float* __restrict__ gray, double* __restrict__ acc,
    unsigned int* __restrict__ hist)
{
    __shared__ unsigned int lh[4][256];
    __shared__ double red[4][3];

    const int t = threadIdx.x;
    const int b = blockIdx.y;
    const int x = blockIdx.x;
    const int lane = t & 63;
    const int w = t >> 6;

    #pragma unroll
    for (int i = 0; i < 4; ++i) lh[i][t] = 0u;
    __syncthreads();

    const float4* rp = (const float4*)(rgb + (size_t)b * 3 * HW);
    const float4* gp = rp + (HW / 4);
    const float4* bp = rp + 2 * (HW / 4);
    const float4* dp = (const float4*)(depth + (size_t)b * HW);
    float4* gw = (float4*)(gray + (size_t)b * HW);

    const int base = x * 1024 + t;
    float dnf = 0.f, dsf = 0.f, dqf = 0.f;

    #pragma unroll
    for (int i = 0; i < 4; ++i) {
        const int idx = base + i * 256;
        const float4 r4 = rp[idx];
        const float4 g4 = gp[idx];
        const float4 b4 = bp[idx];
        const float4 d4 = dp[idx];
        float4 g;
        g.x = 0.299f * r4.x + 0.587f * g4.x + 0.114f * b4.x;
        g.y = 0.299f * r4.y + 0.587f * g4.y + 0.114f * b4.y;
        g.z = 0.299f * r4.z + 0.587f * g4.z + 0.114f * b4.z;
        g.w = 0.299f * r4.w + 0.587f * g4.w + 0.114f * b4.w;
        gw[idx] = g;
        atomicAdd(&lh[w][(int)fminf(fmaxf(g.x * 255.f, 0.f), 255.f)], 1u);
        atomicAdd(&lh[w][(int)fminf(fmaxf(g.y * 255.f, 0.f), 255.f)], 1u);
        atomicAdd(&lh[w][(int)fminf(fmaxf(g.z * 255.f, 0.f), 255.f)], 1u);
        atomicAdd(&lh[w][(int)fminf(fmaxf(g.w * 255.f, 0.f), 255.f)], 1u);
        if (d4.x > 0.f) { dnf += 1.f; dsf += d4.x; dqf += d4.x * d4.x; }
        if (d4.y > 0.f) { dnf += 1.f; dsf += d4.y; dqf += d4.y * d4.y; }
        if (d4.z > 0.f) { dnf += 1.f; dsf += d4.z; dqf += d4.z * d4.z; }
        if (d4.w > 0.f) { dnf += 1.f; dsf += d4.w; dqf += d4.w * d4.w; }
    }

    double z2 = (double)dnf, z3 = (double)dsf, z4 = (double)dqf;
    for (int off = 32; off > 0; off >>= 1) {
        z2 += __shfl_down(z2, off, 64);
        z3 += __shfl_down(z3, off, 64);
        z4 += __shfl_down(z4, off, 64);
    }
    if (lane == 0) { red[w][0] = z2; red[w][1] = z3; red[w][2] = z4; }
    __syncthreads();   // covers lh atomics and red writes

    const unsigned int hsum = lh[0][t] + lh[1][t] + lh[2][t] + lh[3][t];
    atomicAdd(&hist[b * 256 + t], hsum);
    if (t < 3) {
        const double v = red[0][t] + red[1][t] + red[2][t] + red[3][t];
        atomicAdd(&acc[64 + t * 32 + b], v);
    }
}

// ---------------- k2: Laplacian moments on the gray plane ----------------
// Grid 32 x 32. Block = 4 waves x 4 rows. Wave owns full 512-wide rows;
// lane owns cols [4l..4l+3] (A) and [256+4l..+3] (B). 6 rows preloaded to
// registers (12 independent dwordx4), seams via shuffles (R7-verified).
__global__ __launch_bounds__(256, 4) void lap_kernel(
    const float* __restrict__ gray, double* __restrict__ acc)
{
    __shared__ double red[4][2];

    const int t = threadIdx.x;
    const int b = blockIdx.y;
    const int s = blockIdx.x;
    const int lane = t & 63;
    const int w = t >> 6;

    const float* gp = gray + (size_t)b * HW;
    const int rb = s * 16 + w * 4;        // first owned row

    float gr[6][8];
    #pragma unroll
    for (int k = 0; k < 6; ++k) {
        const int r = rb - 1 + k;
        if ((unsigned)r < IMG_H) {        // wave-uniform
            const size_t o = (size_t)r * IMG_W + 4 * lane;
            const float4 a = *(const float4*)(gp + o);
            const float4 c = *(const float4*)(gp + o + 256);
            gr[k][0] = a.x; gr[k][1] = a.y; gr[k][2] = a.z; gr[k][3] = a.w;
            gr[k][4] = c.x; gr[k][5] = c.y; gr[k][6] = c.z; gr[k][7] = c.w;
        } else {
            #pragma unroll
            for (int j = 0; j < 8; ++j) gr[k][j] = 0.f;
        }
    }

    float s1 = 0.f, s2 = 0.f;
    #pragma unroll
    for (int j = 0; j < 4; ++j) {
        const float* up = gr[j];
        const float* gc = gr[j + 1];
        const float* dn = gr[j + 2];

        float lA = __shfl_up(gc[3], 1, 64);
        if (lane == 0) lA = 0.f;
        float rA = __shfl_down(gc[0], 1, 64);
        const float seamR = __shfl(gc[4], 0, 64);    // col 256
        if (lane == 63) rA = seamR;
        float lB = __shfl_up(gc[7], 1, 64);
        const float seamL = __shfl(gc[3], 63, 64);   // col 255
        if (lane == 0) lB = seamL;
        float rB = __shfl_down(gc[4], 1, 64);
        if (lane == 63) rB = 0.f;

        #pragma unroll
        for (int k = 0; k < 8; ++k) {
            float left, right;
            if (k == 0)      { left = lA;        right = gc[1]; }
            else if (k == 3) { left = gc[2];     right = rA; }
            else if (k == 4) { left = lB;        right = gc[5]; }
            else if (k == 7) { left = gc[6];     right = rB; }
            else             { left = gc[k - 1]; right = gc[k + 1]; }
            const float lap = up[k] + dn[k] + left + right - 4.f * gc[k];
            s1 += lap;
            s2 += lap * lap;
        }
    }

    double z0 = (double)s1, z1 = (double)s2;
    for (int off = 32; off > 0; off >>= 1) {
        z0 += __shfl_down(z0, off, 64);
        z1 += __shfl_down(z1, off, 64);
    }
    if (lane == 0) { red[w][0] = z0; red[w][1] = z1; }
    __syncthreads();
    if (t < 2) {
        const double v = red[0][t] + red[1][t] + red[2][t] + red[3][t];
        atomicAdd(&acc[t * 32 + b], v);
    }
}

// ---------------- k3: finalize ----------------
__global__ __launch_bounds__(256) void final_kernel(
    const double* __restrict__ acc,
    const unsigned int* __restrict__ hist,
    float* __restrict__ out)
{
    __shared__ float part[256];
    const int t = threadIdx.x;
    const int b = t >> 3;        // 0..31
    const int sl = t & 7;        // 8 slices of 32 bins
    float e = 0.f;
    #pragma unroll
    for (int i = 0; i < 32; ++i) {
        const float p = (float)hist[b * 256 + sl * 32 + i] * (1.0f / (float)HW);
        e += p * log2f(p + 1e-4f);
    }
    part[t] = e;
    __syncthreads();

    if (t < NB) {
        float es = 0.f;
        #pragma unroll
        for (int i = 0; i < 8; ++i) es += part[t * 8 + i];
        const double entropy = -(double)es;
        const double N = (double)HW;

        const double ls = acc[t], lq = acc[32 + t];
        const double lvar = (lq - ls * ls / N) / (N - 1.0);
        const double clarity = lvar / (1000.0 + 1e-4);
        const double uniformity = 1.0 / (entropy + 1e-4);
        const double rgb_conf = 0.5 * (clarity + uniformity);

        const double n = acc[64 + t], sdep = acc[96 + t], q = acc[128 + t];
        const double mean = sdep / fmax(n, 1.0);
        const double sq = q - 2.0 * mean * sdep + mean * mean * n;
        const double var = sq / fmax(n - 1.0, 1.0);
        const double stdd = sqrt(fmax(var, 0.0));
        const double noise = (n > 0.0) ? stdd : 1.0;
        const double density = n / N;
        const double depth_conf = 0.5 * (density / (10000.0 + 1e-4) + 1.0 / (noise + 1e-4));

        const double denom = rgb_conf + depth_conf + 1e-4;
        out[t]      = (float)(rgb_conf / denom);
        out[NB + t] = (float)(depth_conf / denom);
    }
}

extern "C" void kernel_launch(void* const* d_in, const int* in_sizes, int n_in,
                              void* d_out, int out_size, void* d_ws, size_t ws_size,
                              hipStream_t stream) {
    const float* rgb   = (const float*)d_in[0];
    const float* depth = (const float*)d_in[1];
    float* out = (float*)d_out;

    double* acc = (double*)d_ws;
    unsigned int* hist = (unsigned int*)((char*)d_ws + ACC_DOUBLES * 8);
    float* gray = (float*)((char*)d_ws + GRAY_OFF);

    hipMemsetAsync(d_ws, 0, ZERO_BYTES, stream);

    gray_hist_depth_kernel<<<dim3(64, NB), 256, 0, stream>>>(rgb, depth, gray, acc, hist);
    lap_kernel<<<dim3(32, NB), 256, 0, stream>>>(gray, acc);
    final_kernel<<<1, 256, 0, stream>>>(acc, hist, out);
}